// Round 7
// baseline (222.078 us; speedup 1.0000x reference)
//
#include <hip/hip_runtime.h>

namespace {
constexpr int B = 2, H = 512, W = 512;
constexpr int KH = 32, KW = 32, K = 1024;
constexpr int HW = H * W;
constexpr int NBLOCKS = 256;           // 1 block/CU -> all blocks co-resident for any VGPR<=256
constexpr float YX_SCALE = 0.15625f;   // max(Kh/(0.4*H), Kw/(0.4*W)) == exactly 0.15625 in f32
constexpr float LAB_SCALE = 0.26f;
}

// ---------------------------------------------------------------------------
// Wave64 sum via DPP (HW-verified round 2). Full sum lands in lanes 48..63.
// ---------------------------------------------------------------------------
template <int CTRL>
__device__ __forceinline__ float dpp_add(float v) {
  int r = __builtin_amdgcn_update_dpp(0, __float_as_int(v), CTRL, 0xF, 0xF, true);
  return v + __int_as_float(r);
}
__device__ __forceinline__ float wave_sum64(float v) {
  v = dpp_add<0xB1>(v);    // quad_perm xor1
  v = dpp_add<0x4E>(v);    // quad_perm xor2
  v = dpp_add<0x141>(v);   // row_half_mirror
  v = dpp_add<0x140>(v);   // row_mirror
  v = dpp_add<0x142>(v);   // row_bcast15
  v = dpp_add<0x143>(v);   // row_bcast31
  return v;                // lanes 48..63 hold the 64-lane total
}

__device__ __forceinline__ float fast_rcp(float x) { return __builtin_amdgcn_rcpf(x); }

// Distributed gather of the 9 neighbor superpixels' {wsum, 5 feature sums}:
// 54 lanes each own one (neighbor, component) pair and sum <=9 cell partials.
__device__ __forceinline__ float gather54(const float* __restrict__ pin,
                                          int b, int ki, int kj, int lane) {
  float g = 0.0f;
  const int n = lane / 6, comp = lane % 6;
  const int nki = ki + n / 3 - 1, nkj = kj + n % 3 - 1;
  if ((unsigned)nki < (unsigned)KH && (unsigned)nkj < (unsigned)KW) {
#pragma unroll
    for (int j = 0; j < 9; ++j) {
      const int ci = nki - (j / 3 - 1), cj = nkj - (j % 3 - 1);
      if ((unsigned)ci < (unsigned)KH && (unsigned)cj < (unsigned)KW)
        g += pin[(size_t)((b << 10) + (ci << 5) + cj) * 54 + j * 6 + comp];
    }
  }
  return g;
}

// ---------------------------------------------------------------------------
// Software grid barrier: device-scope atomics + agent fences. One counter per
// sync point (no reset -> no reuse races). Bounded spin: on pathological
// failure we fall through (validation fails loudly) instead of hanging the
// container.
// ---------------------------------------------------------------------------
__device__ __forceinline__ void grid_barrier(unsigned* __restrict__ ctr, int idx) {
  __syncthreads();                      // block's stores drained (vmcnt 0 at barrier)
  if (threadIdx.x == 0) {
    __threadfence();                    // agent-scope release: L2 writeback
    atomicAdd(&ctr[idx], 1u);          // device-scope RMW at coherence point
    unsigned spins = 0;
    while (__hip_atomic_load(&ctr[idx], __ATOMIC_ACQUIRE, __HIP_MEMORY_SCOPE_AGENT)
           < (unsigned)NBLOCKS) {
      __builtin_amdgcn_s_sleep(2);
      if (++spins > 2000000u) break;    // ~0.1s bail-out; breaks correctness, not the GPU
    }
    __threadfence();                    // agent-scope acquire: invalidate stale lines
  }
  __syncthreads();
}

// Zero the barrier counters (d_ws is re-poisoned to 0xAA before every launch).
__global__ void ssn_zero(unsigned* __restrict__ ctr) {
  if (threadIdx.x < 8) ctr[threadIdx.x] = 0u;
}

// ---------------------------------------------------------------------------
// Mega kernel: init -> 4 fused assoc+update passes -> final, one launch.
// 256 blocks x 256 threads; each wave owns TWO 16x16 cells; LAB stays in
// registers (24 VGPR/lane) across all phases.
// ---------------------------------------------------------------------------
__global__ __launch_bounds__(256) void ssn_mega(
    const float* __restrict__ lab,
    float* __restrict__ outPFeat, float* __restrict__ outSpFeat,
    float* __restrict__ outAssoc, float* __restrict__ outIdx,
    float* __restrict__ pA, float* __restrict__ pB,
    unsigned* __restrict__ ctr) {
  __shared__ float sfl[4][2][54];
  const int lane = threadIdx.x & 63;
  const int wid = threadIdx.x >> 6;
  const int wg = blockIdx.x * 4 + wid;    // wave-global id, 0..1023

  // ---- phase 0: load LAB into regs, write pFeat, seed pA self-slots ----
  float l0[2][4], l1[2][4], l2[2][4];
#pragma unroll
  for (int cc = 0; cc < 2; ++cc) {
    const int cell = (wg << 1) + cc;      // 0..2047
    const int b = cell >> 10;
    const int k = cell & (K - 1);
    const int ki = k >> 5, kj = k & 31;
    const float* labB = lab + (size_t)b * 3 * HW;
    float s0 = 0, s1 = 0, s2 = 0, s3 = 0, s4 = 0;
#pragma unroll
    for (int px = 0; px < 4; ++px) {
      const int t = lane + px * 64;
      const int y = (ki << 4) + (t >> 4);
      const int x = (kj << 4) + (t & 15);
      const int pix = y * W + x;
      l0[cc][px] = LAB_SCALE * labB[pix];
      l1[cc][px] = LAB_SCALE * labB[HW + pix];
      l2[cc][px] = LAB_SCALE * labB[2 * HW + pix];
      const float f0 = YX_SCALE * (float)y, f1 = YX_SCALE * (float)x;
      float* po = outPFeat + (size_t)b * 5 * HW + pix;
      po[0] = f0;
      po[HW] = f1;
      po[2 * HW] = l0[cc][px];
      po[3 * HW] = l1[cc][px];
      po[4 * HW] = l2[cc][px];
      s0 += f0; s1 += f1; s2 += l0[cc][px]; s3 += l1[cc][px]; s4 += l2[cc][px];
    }
    s0 = wave_sum64(s0); s1 = wave_sum64(s1); s2 = wave_sum64(s2);
    s3 = wave_sum64(s3); s4 = wave_sum64(s4);
    float* pc = pA + (size_t)cell * 54;
    if (lane < 54 && (lane < 24 || lane > 29)) pc[lane] = 0.0f;  // non-self slots
    if (lane == 63) {   // self slot j=4: {count, feature sums}
      pc[24] = 256.0f;
      pc[25] = s0; pc[26] = s1; pc[27] = s2; pc[28] = s3; pc[29] = s4;
    }
  }
  grid_barrier(ctr, 0);

  // ---- phases 1..4: fused assoc + scatter-accumulate ----
  const float* cur = pA;
  float* nxt = pB;
#pragma unroll 1
  for (int it = 0; it < 4; ++it) {
#pragma unroll
    for (int cc = 0; cc < 2; ++cc) {
      const int cell = (wg << 1) + cc;
      const int b = cell >> 10;
      const int k = cell & (K - 1);
      const int ki = k >> 5, kj = k & 31;
      if (lane < 54) sfl[wid][cc][lane] = gather54(cur, b, ki, kj, lane);
    }
    __syncthreads();

#pragma unroll
    for (int cc = 0; cc < 2; ++cc) {
      const int cell = (wg << 1) + cc;
      const int b = cell >> 10;
      const int k = cell & (K - 1);
      const int ki = k >> 5, kj = k & 31;

      float sf[9][5];
      bool valid[9];
#pragma unroll
      for (int n = 0; n < 9; ++n) {
        const int ni = ki + n / 3 - 1, nj = kj + n % 3 - 1;
        valid[n] = ((unsigned)ni < (unsigned)KH) && ((unsigned)nj < (unsigned)KW);
        const float inv = fast_rcp(fmaxf(sfl[wid][cc][n * 6], 1e-10f));
#pragma unroll
        for (int c = 0; c < 5; ++c) sf[n][c] = sfl[wid][cc][n * 6 + 1 + c] * inv;
      }

      float acc[54];
#pragma unroll
      for (int i = 0; i < 54; ++i) acc[i] = 0.0f;

#pragma unroll
      for (int px = 0; px < 4; ++px) {
        const int t = lane + px * 64;
        const int y = (ki << 4) + (t >> 4);
        const int x = (kj << 4) + (t & 15);
        float f[5];
        f[0] = YX_SCALE * (float)y;
        f[1] = YX_SCALE * (float)x;
        f[2] = l0[cc][px]; f[3] = l1[cc][px]; f[4] = l2[cc][px];

        float d[9];
#pragma unroll
        for (int j = 0; j < 9; ++j) {
          float t0 = f[0] - sf[j][0];
          float dd = t0 * t0;
#pragma unroll
          for (int c = 1; c < 5; ++c) {
            const float tc = f[c] - sf[j][c];
            dd = fmaf(tc, tc, dd);
          }
          d[j] = dd;
        }
        float m = 1e30f;
#pragma unroll
        for (int j = 0; j < 9; ++j)
          if (valid[j]) m = fminf(m, d[j]);
        float e[9], sum = 0.0f;
#pragma unroll
        for (int j = 0; j < 9; ++j) {
          e[j] = valid[j] ? __expf(m - d[j]) : 0.0f;
          sum += e[j];
        }
        const float inv = fast_rcp(sum);
#pragma unroll
        for (int j = 0; j < 9; ++j) {
          const float w = e[j] * inv;
          acc[j * 6 + 0] += w;
#pragma unroll
          for (int c = 0; c < 5; ++c)
            acc[j * 6 + 1 + c] = fmaf(w, f[c], acc[j * 6 + 1 + c]);
        }
      }

#pragma unroll
      for (int i = 0; i < 54; ++i) acc[i] = wave_sum64(acc[i]);
      if (lane == 63) {
        float* p = nxt + (size_t)cell * 54;
#pragma unroll
        for (int i = 0; i < 54; ++i) p[i] = acc[i];
      }
    }
    grid_barrier(ctr, 1 + it);
    const float* tmp = cur; cur = nxt; nxt = (float*)tmp;
  }

  // ---- phase 5: final assoc, spFeat / psp_assoc / final_spIndx outputs ----
#pragma unroll
  for (int cc = 0; cc < 2; ++cc) {
    const int cell = (wg << 1) + cc;
    const int b = cell >> 10;
    const int k = cell & (K - 1);
    const int ki = k >> 5, kj = k & 31;
    if (lane < 54) sfl[wid][cc][lane] = gather54(cur, b, ki, kj, lane);
  }
  __syncthreads();

#pragma unroll
  for (int cc = 0; cc < 2; ++cc) {
    const int cell = (wg << 1) + cc;
    const int b = cell >> 10;
    const int k = cell & (K - 1);
    const int ki = k >> 5, kj = k & 31;

    if (lane == 0) {  // own-superpixel spFeat, layout (B,5,K)
      const float inv4 = 1.0f / fmaxf(sfl[wid][cc][24], 1e-10f);
#pragma unroll
      for (int c = 0; c < 5; ++c)
        outSpFeat[((size_t)b * 5 + c) * K + k] = sfl[wid][cc][25 + c] * inv4;
    }

    float sf[9][5];
    bool valid[9];
#pragma unroll
    for (int n = 0; n < 9; ++n) {
      const int ni = ki + n / 3 - 1, nj = kj + n % 3 - 1;
      valid[n] = ((unsigned)ni < (unsigned)KH) && ((unsigned)nj < (unsigned)KW);
      const float inv = 1.0f / fmaxf(sfl[wid][cc][n * 6], 1e-10f);
#pragma unroll
      for (int c = 0; c < 5; ++c) sf[n][c] = sfl[wid][cc][n * 6 + 1 + c] * inv;
    }

#pragma unroll
    for (int px = 0; px < 4; ++px) {
      const int t = lane + px * 64;
      const int y = (ki << 4) + (t >> 4);
      const int x = (kj << 4) + (t & 15);
      const int pix = y * W + x;
      float f[5];
      f[0] = YX_SCALE * (float)y;
      f[1] = YX_SCALE * (float)x;
      f[2] = l0[cc][px]; f[3] = l1[cc][px]; f[4] = l2[cc][px];

      float d[9];
#pragma unroll
      for (int j = 0; j < 9; ++j) {
        float t0 = f[0] - sf[j][0];
        float dd = t0 * t0;
#pragma unroll
        for (int c = 1; c < 5; ++c) {
          const float tc = f[c] - sf[j][c];
          dd = fmaf(tc, tc, dd);
        }
        d[j] = dd;
      }
      float m = 1e30f;
#pragma unroll
      for (int j = 0; j < 9; ++j)
        if (valid[j]) m = fminf(m, d[j]);
      float e[9], sum = 0.0f;
#pragma unroll
      for (int j = 0; j < 9; ++j) {
        e[j] = valid[j] ? __expf(m - d[j]) : 0.0f;
        sum += e[j];
      }
      const float inv = 1.0f / sum;   // exact IEEE div on the direct output path

      float* oa = outAssoc + (size_t)b * 9 * HW + pix;
#pragma unroll
      for (int j = 0; j < 9; ++j) oa[(size_t)j * HW] = e[j] * inv;

      // argmax(prob) == first argmin(dist among valid); exp is monotone
      int bestj = 4;
      float bestd = 1e30f;
#pragma unroll
      for (int j = 0; j < 9; ++j)
        if (valid[j] && d[j] < bestd) { bestd = d[j]; bestj = j; }
      const int bi = ki + bestj / 3 - 1;
      const int bj = kj + bestj % 3 - 1;
      outIdx[(size_t)b * HW + pix] = (float)(bi * KW + bj);
    }
  }
}

// ---------------------------------------------------------------------------
extern "C" void kernel_launch(void* const* d_in, const int* in_sizes, int n_in,
                              void* d_out, int out_size, void* d_ws, size_t ws_size,
                              hipStream_t stream) {
  const float* lab = (const float*)d_in[0];
  // d_in[1] (init_spIndx) is the deterministic regular grid; recomputed on device.

  float* out = (float*)d_out;
  float* outPFeat = out;                   // 2*5*512*512 = 2621440
  float* outSpFeat = outPFeat + 2621440;   // 2*5*1024    = 10240
  float* outAssoc = outSpFeat + 10240;     // 2*9*512*512 = 4718592
  float* outIdx = outAssoc + 4718592;      // 2*512*512   = 524288

  float* pA = (float*)d_ws;                // [B*K][9][6] = 442 KB
  float* pB = pA + (size_t)B * K * 54;     // ping-pong partner
  unsigned* ctr = (unsigned*)(pB + (size_t)B * K * 54);  // 8 barrier counters

  ssn_zero<<<1, 64, 0, stream>>>(ctr);
  ssn_mega<<<NBLOCKS, 256, 0, stream>>>(lab, outPFeat, outSpFeat, outAssoc,
                                        outIdx, pA, pB, ctr);
}

// Round 9
// 117.735 us; speedup vs baseline: 1.8863x; 1.8863x over previous
//
#include <hip/hip_runtime.h>

namespace {
constexpr int B = 2, H = 512, W = 512;
constexpr int KH = 32, KW = 32, K = 1024;
constexpr int HW = H * W;
constexpr float YX_SCALE = 0.15625f;   // max(Kh/(0.4*H), Kw/(0.4*W)) == exactly 0.15625 in f32
constexpr float LAB_SCALE = 0.26f;
}

// ---------------------------------------------------------------------------
// Wave64 sum via DPP (HW-verified rounds 2/7). Full sum lands in lanes 48..63.
// ---------------------------------------------------------------------------
template <int CTRL>
__device__ __forceinline__ float dpp_add(float v) {
  int r = __builtin_amdgcn_update_dpp(0, __float_as_int(v), CTRL, 0xF, 0xF, true);
  return v + __int_as_float(r);
}
__device__ __forceinline__ float wave_sum64(float v) {
  v = dpp_add<0xB1>(v);    // quad_perm xor1
  v = dpp_add<0x4E>(v);    // quad_perm xor2
  v = dpp_add<0x141>(v);   // row_half_mirror
  v = dpp_add<0x140>(v);   // row_mirror
  v = dpp_add<0x142>(v);   // row_bcast15
  v = dpp_add<0x143>(v);   // row_bcast31
  return v;                // lanes 48..63 hold the 64-lane total
}

__device__ __forceinline__ float fast_rcp(float x) { return __builtin_amdgcn_rcpf(x); }

// Distributed gather of the 9 neighbor superpixels' {wsum, 5 feature sums}:
// lane<54 owns one (neighbor, component) pair and sums <=9 cell partials.
__device__ __forceinline__ float gather54(const float* __restrict__ pin,
                                          int b, int ki, int kj, int lane) {
  float g = 0.0f;
  const int n = lane / 6, comp = lane % 6;
  const int nki = ki + n / 3 - 1, nkj = kj + n % 3 - 1;
  if ((unsigned)nki < (unsigned)KH && (unsigned)nkj < (unsigned)KW) {
#pragma unroll
    for (int j = 0; j < 9; ++j) {
      const int ci = nki - (j / 3 - 1), cj = nkj - (j % 3 - 1);
      if ((unsigned)ci < (unsigned)KH && (unsigned)cj < (unsigned)KW)
        g += pin[(size_t)((b << 10) + (ci << 5) + cj) * 54 + j * 6 + comp];
    }
  }
  return g;
}

// ---------------------------------------------------------------------------
// Init (measured-passing round 2): 2048 blocks, 1 cell/block, 1 px/thread.
// Writes pFeat output + seeds partial[A] self slots.
// ---------------------------------------------------------------------------
__global__ __launch_bounds__(256) void ssn_init(const float* __restrict__ lab,
                                                float* __restrict__ outPFeat,
                                                float* __restrict__ partial) {
  const int cell = blockIdx.x;
  const int b = cell >> 10;
  const int k = cell & (K - 1);
  const int ki = k >> 5, kj = k & 31;
  const int t = threadIdx.x;
  const int y = (ki << 4) + (t >> 4);
  const int x = (kj << 4) + (t & 15);
  const int pix = y * W + x;
  const float* labB = lab + (size_t)b * 3 * HW;

  float f[5];
  f[0] = YX_SCALE * (float)y;
  f[1] = YX_SCALE * (float)x;
  f[2] = LAB_SCALE * labB[pix];
  f[3] = LAB_SCALE * labB[HW + pix];
  f[4] = LAB_SCALE * labB[2 * HW + pix];

  float* po = outPFeat + (size_t)b * 5 * HW + pix;
#pragma unroll
  for (int c = 0; c < 5; ++c) po[(size_t)c * HW] = f[c];

  // zero the 48 non-self slots (indices 0..23 and 30..53)
  if (t < 54 && (t < 24 || t >= 30)) partial[(size_t)cell * 54 + t] = 0.0f;

  float s[5];
#pragma unroll
  for (int c = 0; c < 5; ++c) s[c] = wave_sum64(f[c]);
  __shared__ float red[4][5];
  if ((t & 63) == 63) {
#pragma unroll
    for (int c = 0; c < 5; ++c) red[t >> 6][c] = s[c];
  }
  __syncthreads();
  if (t < 5)
    partial[(size_t)cell * 54 + 25 + t] = red[0][t] + red[1][t] + red[2][t] + red[3][t];
  if (t == 5) partial[(size_t)cell * 54 + 24] = 256.0f;
}

// ---------------------------------------------------------------------------
// Update v2: 1024 blocks; block = 2 cells, 2 waves per cell, 2 px/lane.
// Doubles resident waves and halves each wave's serial chain vs round 2.
// ---------------------------------------------------------------------------
__global__ __launch_bounds__(256) void ssn_update2(const float* __restrict__ lab,
                                                   const float* __restrict__ pin,
                                                   float* __restrict__ pout) {
  __shared__ float sfg[2][54];        // gathered neighbor sums per cell
  __shared__ float comb[2][2][54];    // [sub-wave][cell-in-block][54]
  const int lane = threadIdx.x & 63;
  const int wid = threadIdx.x >> 6;
  const int cidx = wid >> 1, sub = wid & 1;
  const int cell = blockIdx.x * 2 + cidx;   // 0 .. B*K-1
  const int b = cell >> 10;
  const int k = cell & (K - 1);
  const int ki = k >> 5, kj = k & 31;

  if (wid < 2 && lane < 54) {
    const int gcell = blockIdx.x * 2 + wid;
    const int gk = gcell & (K - 1);
    sfg[wid][lane] = gather54(pin, gcell >> 10, gk >> 5, gk & 31, lane);
  }
  __syncthreads();

  float sf[9][5];
  bool valid[9];
#pragma unroll
  for (int n = 0; n < 9; ++n) {
    const int ni = ki + n / 3 - 1, nj = kj + n % 3 - 1;
    valid[n] = ((unsigned)ni < (unsigned)KH) && ((unsigned)nj < (unsigned)KW);
    const float inv = fast_rcp(fmaxf(sfg[cidx][n * 6], 1e-10f));
#pragma unroll
    for (int c = 0; c < 5; ++c) sf[n][c] = sfg[cidx][n * 6 + 1 + c] * inv;
  }

  float acc[54];
#pragma unroll
  for (int i = 0; i < 54; ++i) acc[i] = 0.0f;

  const float* labB = lab + (size_t)b * 3 * HW;
#pragma unroll
  for (int pxi = 0; pxi < 2; ++pxi) {
    const int t = lane + sub * 64 + pxi * 128;   // 0..255 unique across the 2 waves
    const int y = (ki << 4) + (t >> 4);
    const int x = (kj << 4) + (t & 15);
    const int pix = y * W + x;
    float f[5];
    f[0] = YX_SCALE * (float)y;
    f[1] = YX_SCALE * (float)x;
    f[2] = LAB_SCALE * labB[pix];
    f[3] = LAB_SCALE * labB[HW + pix];
    f[4] = LAB_SCALE * labB[2 * HW + pix];

    float d[9];
#pragma unroll
    for (int j = 0; j < 9; ++j) {
      float t0 = f[0] - sf[j][0];
      float dd = t0 * t0;
#pragma unroll
      for (int c = 1; c < 5; ++c) {
        const float tc = f[c] - sf[j][c];
        dd = fmaf(tc, tc, dd);
      }
      d[j] = dd;
    }
    float m = 1e30f;
#pragma unroll
    for (int j = 0; j < 9; ++j)
      if (valid[j]) m = fminf(m, d[j]);
    float e[9], sum = 0.0f;
#pragma unroll
    for (int j = 0; j < 9; ++j) {
      e[j] = valid[j] ? __expf(m - d[j]) : 0.0f;
      sum += e[j];
    }
    const float inv = fast_rcp(sum);
#pragma unroll
    for (int j = 0; j < 9; ++j) {
      const float w = e[j] * inv;
      acc[j * 6 + 0] += w;
#pragma unroll
      for (int c = 0; c < 5; ++c)
        acc[j * 6 + 1 + c] = fmaf(w, f[c], acc[j * 6 + 1 + c]);
    }
  }

#pragma unroll
  for (int i = 0; i < 54; ++i) acc[i] = wave_sum64(acc[i]);
  if (lane == 63) {
#pragma unroll
    for (int i = 0; i < 54; ++i) comb[sub][cidx][i] = acc[i];
  }
  __syncthreads();
  if (wid < 2 && lane < 54) {
    const int scell = blockIdx.x * 2 + wid;
    pout[(size_t)scell * 54 + lane] = comb[0][wid][lane] + comb[1][wid][lane];
  }
}

// ---------------------------------------------------------------------------
// Final v2: 2048 blocks, 1 cell/block, 1 px/thread (no accumulation -> max
// parallelism). Emits spFeat (B,5,K), psp_assoc (B,9,H,W), final_spIndx.
// ---------------------------------------------------------------------------
__global__ __launch_bounds__(256) void ssn_final2(const float* __restrict__ lab,
                                                  const float* __restrict__ pin,
                                                  float* __restrict__ outSpFeat,
                                                  float* __restrict__ outAssoc,
                                                  float* __restrict__ outIdx) {
  __shared__ float sfg[54];
  const int tid = threadIdx.x;
  const int cell = blockIdx.x;
  const int b = cell >> 10;
  const int k = cell & (K - 1);
  const int ki = k >> 5, kj = k & 31;

  if (tid < 54) sfg[tid] = gather54(pin, b, ki, kj, tid);
  __syncthreads();

  if (tid < 5) {   // own-superpixel spFeat, layout (B,5,K)
    const float inv4 = 1.0f / fmaxf(sfg[24], 1e-10f);
    outSpFeat[((size_t)b * 5 + tid) * K + k] = sfg[25 + tid] * inv4;
  }

  float sf[9][5];
  bool valid[9];
#pragma unroll
  for (int n = 0; n < 9; ++n) {
    const int ni = ki + n / 3 - 1, nj = kj + n % 3 - 1;
    valid[n] = ((unsigned)ni < (unsigned)KH) && ((unsigned)nj < (unsigned)KW);
    const float inv = 1.0f / fmaxf(sfg[n * 6], 1e-10f);   // exact div (output path)
#pragma unroll
    for (int c = 0; c < 5; ++c) sf[n][c] = sfg[n * 6 + 1 + c] * inv;
  }

  const int y = (ki << 4) + (tid >> 4);
  const int x = (kj << 4) + (tid & 15);
  const int pix = y * W + x;
  const float* labB = lab + (size_t)b * 3 * HW;
  float f[5];
  f[0] = YX_SCALE * (float)y;
  f[1] = YX_SCALE * (float)x;
  f[2] = LAB_SCALE * labB[pix];
  f[3] = LAB_SCALE * labB[HW + pix];
  f[4] = LAB_SCALE * labB[2 * HW + pix];

  float d[9];
#pragma unroll
  for (int j = 0; j < 9; ++j) {
    float t0 = f[0] - sf[j][0];
    float dd = t0 * t0;
#pragma unroll
    for (int c = 1; c < 5; ++c) {
      const float tc = f[c] - sf[j][c];
      dd = fmaf(tc, tc, dd);
    }
    d[j] = dd;
  }
  float m = 1e30f;
#pragma unroll
  for (int j = 0; j < 9; ++j)
    if (valid[j]) m = fminf(m, d[j]);
  float e[9], sum = 0.0f;
#pragma unroll
  for (int j = 0; j < 9; ++j) {
    e[j] = valid[j] ? __expf(m - d[j]) : 0.0f;
    sum += e[j];
  }
  const float inv = 1.0f / sum;   // exact IEEE div on the direct output path

  float* oa = outAssoc + (size_t)b * 9 * HW + pix;
#pragma unroll
  for (int j = 0; j < 9; ++j) oa[(size_t)j * HW] = e[j] * inv;

  // argmax(prob) == first argmin(dist among valid); exp is monotone
  int bestj = 4;
  float bestd = 1e30f;
#pragma unroll
  for (int j = 0; j < 9; ++j)
    if (valid[j] && d[j] < bestd) { bestd = d[j]; bestj = j; }
  const int bi = ki + bestj / 3 - 1;
  const int bj = kj + bestj % 3 - 1;
  outIdx[(size_t)b * HW + pix] = (float)(bi * KW + bj);
}

// ---------------------------------------------------------------------------
extern "C" void kernel_launch(void* const* d_in, const int* in_sizes, int n_in,
                              void* d_out, int out_size, void* d_ws, size_t ws_size,
                              hipStream_t stream) {
  const float* lab = (const float*)d_in[0];
  // d_in[1] (init_spIndx) is the deterministic regular grid; recomputed on device.

  float* out = (float*)d_out;
  float* outPFeat = out;                   // 2*5*512*512 = 2621440
  float* outSpFeat = outPFeat + 2621440;   // 2*5*1024    = 10240
  float* outAssoc = outSpFeat + 10240;     // 2*9*512*512 = 4718592
  float* outIdx = outAssoc + 4718592;      // 2*512*512   = 524288

  float* pA = (float*)d_ws;                // [B*K][9][6] = 442 KB
  float* pB = pA + (size_t)B * K * 54;     // ping-pong partner

  ssn_init<<<B * K, 256, 0, stream>>>(lab, outPFeat, pA);
  ssn_update2<<<B * K / 2, 256, 0, stream>>>(lab, pA, pB);  // pass 1
  ssn_update2<<<B * K / 2, 256, 0, stream>>>(lab, pB, pA);  // pass 2
  ssn_update2<<<B * K / 2, 256, 0, stream>>>(lab, pA, pB);  // pass 3
  ssn_update2<<<B * K / 2, 256, 0, stream>>>(lab, pB, pA);  // pass 4
  ssn_final2<<<B * K, 256, 0, stream>>>(lab, pA, outSpFeat, outAssoc, outIdx);
}